// Round 2
// baseline (1244.651 us; speedup 1.0000x reference)
//
#include <hip/hip_runtime.h>
#include <math.h>

// InterAttention: B=64, L1=L2=512, D=256, fp32.
// Pipeline (all on `stream`, scratch in d_ws, 4 x 64MiB buffers reused):
//   T  = leaky(X@W1+b1)              X = r1 rows then r2 rows   -> buf0
//   H  = leaky(T@W2+b2) * mask                                  -> buf1
//   S  = h1 @ h2^T   (batched NT)                               -> buf0
//   O1 = rowsoftmax(S) gated                                    -> buf2
//   O2 = colsoftmax(S) gated                                    -> buf3
//   RC = [O1@h2 ; O2^T@h1]                                      -> buf0
//   C1 = leaky([H|RC]@Wc1+bc1)   (dual-A K-concat)              -> buf2
//   RCMP = leaky(C1@Wc2+bc2)                                    -> buf3
//   out = masked mean-pool(RCMP)                                -> d_out

constexpr int TM = 128, TN = 128, TK = 32;   // TK=32: halves barrier count vs 16;
                                             // LDS 33.8KB -> still 4 blocks/CU (VGPR-capped anyway)
constexpr long NF = 16777216L;               // floats per ws buffer (64*512*512 == 65536*256)

__device__ __forceinline__ float leaky(float x) { return x > 0.f ? x : 0.01f * x; }

// C[m,n] = sum_k As[k,m]*Bs[k,n]
// AMODE 0: global A is [M,K] (k contig, transpose to LDS); 1: A is [K,M] (direct)
// BMODE 0: global B is [K,N] (direct); 1: B is [N,K] (transpose to LDS)
// EPI   0: plain store; 1: leaky(x+bias); 2: leaky(x+bias)*rowmask
// DUALA 1: K-concat of two A sources (k < K1 from A, else from A2), same lda
template<int AMODE, int BMODE, int EPI, int DUALA>
__global__ __launch_bounds__(256)
void gemm_k(const float* __restrict__ A, const float* __restrict__ A2,
            const float* __restrict__ Bm, const float* __restrict__ bias,
            float* __restrict__ C, const int* __restrict__ rmask,
            int M, int N, int K, int K1,
            int lda, int ldb, int ldc,
            long sA, long sB, long sC)
{
    __shared__ float As[TK][TM + 4];
    __shared__ float Bs[TK][TN + 4];
    constexpr int NI = (TM * TK / 4) / 256;  // float4 staging iterations per operand
    constexpr int KQ = TK / 4;               // float4 quads along k per row
    const int z = blockIdx.z;
    A += (long)z * sA; Bm += (long)z * sB; C += (long)z * sC;
    const int m0 = blockIdx.x * TM, n0 = blockIdx.y * TN;
    const int tid = threadIdx.x;
    const int tm = tid >> 4, tn = tid & 15;      // 16x16 threads, 8x8 micro-tile
    float acc[8][8];
#pragma unroll
    for (int i = 0; i < 8; ++i)
#pragma unroll
        for (int j = 0; j < 8; ++j) acc[i][j] = 0.f;

    for (int k0 = 0; k0 < K; k0 += TK) {
        if (AMODE == 0) {
            const float* Ab = A; int kk0 = k0;
            if (DUALA) { if (k0 >= K1) { Ab = A2; kk0 = k0 - K1; } }
#pragma unroll
            for (int i = 0; i < NI; ++i) {
                int slot = tid + i * 256;        // TM rows x (TK/4) k-quads
                int row = slot / KQ;
                int kq = (slot % KQ) << 2;
                float4 v = *(const float4*)(Ab + (long)(m0 + row) * lda + kk0 + kq);
                As[kq + 0][row] = v.x; As[kq + 1][row] = v.y;
                As[kq + 2][row] = v.z; As[kq + 3][row] = v.w;
            }
        } else {
#pragma unroll
            for (int i = 0; i < NI; ++i) {
                int slot = tid + i * 256;        // TK k x (TM/4) m-quads
                int kk = slot >> 5;
                int mq = (slot & 31) << 2;
                *(float4*)&As[kk][mq] = *(const float4*)(A + (long)(k0 + kk) * lda + m0 + mq);
            }
        }
        if (BMODE == 0) {
#pragma unroll
            for (int i = 0; i < NI; ++i) {
                int slot = tid + i * 256;
                int kk = slot >> 5;
                int nq = (slot & 31) << 2;
                *(float4*)&Bs[kk][nq] = *(const float4*)(Bm + (long)(k0 + kk) * ldb + n0 + nq);
            }
        } else {
#pragma unroll
            for (int i = 0; i < NI; ++i) {
                int slot = tid + i * 256;
                int row = slot / KQ;
                int kq = (slot % KQ) << 2;
                float4 v = *(const float4*)(Bm + (long)(n0 + row) * ldb + k0 + kq);
                Bs[kq + 0][row] = v.x; Bs[kq + 1][row] = v.y;
                Bs[kq + 2][row] = v.z; Bs[kq + 3][row] = v.w;
            }
        }
        __syncthreads();
#pragma unroll 8
        for (int k = 0; k < TK; ++k) {
            float4 a0 = *(const float4*)&As[k][tm * 8];
            float4 a1 = *(const float4*)&As[k][tm * 8 + 4];
            float4 b0 = *(const float4*)&Bs[k][tn * 8];
            float4 b1 = *(const float4*)&Bs[k][tn * 8 + 4];
            float av[8] = { a0.x, a0.y, a0.z, a0.w, a1.x, a1.y, a1.z, a1.w };
            float bv[8] = { b0.x, b0.y, b0.z, b0.w, b1.x, b1.y, b1.z, b1.w };
#pragma unroll
            for (int i = 0; i < 8; ++i)
#pragma unroll
                for (int j = 0; j < 8; ++j)
                    acc[i][j] = fmaf(av[i], bv[j], acc[i][j]);
        }
        __syncthreads();
    }

    float bv[8];
    if (EPI >= 1) {
#pragma unroll
        for (int j = 0; j < 8; ++j) bv[j] = bias[n0 + tn * 8 + j];
    }
#pragma unroll
    for (int i = 0; i < 8; ++i) {
        int row = m0 + tm * 8 + i;
        float rm = 1.f;
        if (EPI == 2) rm = (float)rmask[row];
#pragma unroll
        for (int j = 0; j < 8; ++j) {
            float v = acc[i][j];
            if (EPI >= 1) v = leaky(v + bv[j]);
            if (EPI == 2) v *= rm;
            acc[i][j] = v;
        }
        *(float4*)(C + (long)row * ldc + n0 + tn * 8)     = *(float4*)&acc[i][0];
        *(float4*)(C + (long)row * ldc + n0 + tn * 8 + 4) = *(float4*)&acc[i][4];
    }
}

// One block per (b,l) row of S; softmax over 512 columns, gated by masks.
__global__ __launch_bounds__(256)
void softmax_row_k(const float* __restrict__ S, const int* __restrict__ m1,
                   const int* __restrict__ m2, float* __restrict__ O)
{
    __shared__ float red[4];
    const int gr = blockIdx.x;
    const int b = gr >> 9, l = gr & 511;
    const float* srow = S + (long)gr * 512;
    float* orow = O + (long)gr * 512;
    const int tid = threadIdx.x;
    const int c0 = tid, c1 = tid + 256;
    const int rowvalid = m1[(long)b * 512 + l];
    const int* m2b = m2 + (long)b * 512;
    const int a0 = m2b[c0], a1 = m2b[c1];
    const float v0 = srow[c0], v1 = srow[c1];
    float x = fmaxf(a0 ? v0 : -3e38f, a1 ? v1 : -3e38f);
#pragma unroll
    for (int o = 32; o; o >>= 1) x = fmaxf(x, __shfl_xor(x, o));
    if ((tid & 63) == 0) red[tid >> 6] = x;
    __syncthreads();
    const float mx = fmaxf(fmaxf(red[0], red[1]), fmaxf(red[2], red[3]));
    __syncthreads();
    if (!rowvalid || mx < -1e30f) { orow[c0] = 0.f; orow[c1] = 0.f; return; }
    float p0 = a0 ? expf(v0 - mx) : 0.f;
    float p1 = a1 ? expf(v1 - mx) : 0.f;
    float s = p0 + p1;
#pragma unroll
    for (int o = 32; o; o >>= 1) s += __shfl_xor(s, o);
    if ((tid & 63) == 0) red[tid >> 6] = s;
    __syncthreads();
    const float inv = 1.f / (red[0] + red[1] + red[2] + red[3]);
    orow[c0] = p0 * inv;
    orow[c1] = p1 * inv;
}

// One block per (b, 64-col tile): online column softmax (axis=l), coalesced.
__global__ __launch_bounds__(256)
void softmax_col_k(const float* __restrict__ S, const int* __restrict__ m1,
                   const int* __restrict__ m2, float* __restrict__ O)
{
    __shared__ float smM[4][64], smS[4][64], colM[64], colI[64];
    const int b = blockIdx.y;
    const int c0 = blockIdx.x * 64;
    const int tid = threadIdx.x;
    const int c = tid & 63, rq = tid >> 6;
    const int* m1b = m1 + (long)b * 512;
    const int* m2b = m2 + (long)b * 512;
    const float* Sb = S + (long)b * 512 * 512;
    float* Ob = O + (long)b * 512 * 512;
    float mt = -3e38f, st = 0.f;
    for (int r = rq; r < 512; r += 4) {
        if (m1b[r]) {
            float v = Sb[(long)r * 512 + c0 + c];
            if (v <= mt) st += expf(v - mt);
            else { st = st * expf(mt - v) + 1.f; mt = v; }
        }
    }
    smM[rq][c] = mt; smS[rq][c] = st;
    __syncthreads();
    if (rq == 0) {
        float M = fmaxf(fmaxf(smM[0][c], smM[1][c]), fmaxf(smM[2][c], smM[3][c]));
        float ssum = 0.f;
#pragma unroll
        for (int i = 0; i < 4; ++i) {
            float mi = smM[i][c];
            if (mi > -1e30f) ssum += smS[i][c] * expf(mi - M);
        }
        colM[c] = M;
        colI[c] = (ssum > 0.f) ? 1.f / ssum : 0.f;
    }
    __syncthreads();
    const float M = colM[c], inv = colI[c];
    const int ac = m2b[c0 + c];
    for (int r = rq; r < 512; r += 4) {
        float o = 0.f;
        if (ac && m1b[r] && inv != 0.f)
            o = expf(Sb[(long)r * 512 + c0 + c] - M) * inv;
        Ob[(long)r * 512 + c0 + c] = o;
    }
}

// One block per (seg,b): out[b,:] = sum_l mask*RCMP[l,:] / count
__global__ __launch_bounds__(256)
void pool_k(const float* __restrict__ RC, const int* __restrict__ m1,
            const int* __restrict__ m2, float* __restrict__ out)
{
    const int seg = blockIdx.x >> 6, b = blockIdx.x & 63;
    const int* mb = (seg ? m2 : m1) + (long)b * 512;
    const float* base = RC + ((long)seg * 32768 + (long)b * 512) * 256;
    const int n = threadIdx.x;
    float acc = 0.f; int cnt = 0;
    for (int l = 0; l < 512; ++l) {
        int m = mb[l];
        if (m) { cnt++; acc += base[(long)l * 256 + n]; }
    }
    out[((long)seg * 64 + b) * 256 + n] = acc / (float)cnt;
}

extern "C" void kernel_launch(void* const* d_in, const int* in_sizes, int n_in,
                              void* d_out, int out_size, void* d_ws, size_t ws_size,
                              hipStream_t stream)
{
    const float* r1  = (const float*)d_in[0];
    const float* r2  = (const float*)d_in[1];
    const int*   mk1 = (const int*)d_in[2];
    const int*   mk2 = (const int*)d_in[3];
    const float* W1  = (const float*)d_in[4];
    const float* b1  = (const float*)d_in[5];
    const float* W2  = (const float*)d_in[6];
    const float* b2  = (const float*)d_in[7];
    const float* Wc1 = (const float*)d_in[8];
    const float* bc1 = (const float*)d_in[9];
    const float* Wc2 = (const float*)d_in[10];
    const float* bc2 = (const float*)d_in[11];
    float* out = (float*)d_out;
    float* ws = (float*)d_ws;
    float* buf0 = ws;
    float* buf1 = ws + NF;
    float* buf2 = ws + 2 * NF;
    float* buf3 = ws + 3 * NF;
    const long SEG = 32768L * 256;     // floats per row-segment
    dim3 blk(256);

    // MLP layer 1: T = leaky(X@W1+b1)                      (T = buf0)
    gemm_k<0,0,1,0><<<dim3(256,2,1), blk, 0, stream>>>(r1, nullptr, W1, b1, buf0,       nullptr, 32768,256,256,0, 256,256,256, 0,0,0);
    gemm_k<0,0,1,0><<<dim3(256,2,1), blk, 0, stream>>>(r2, nullptr, W1, b1, buf0 + SEG, nullptr, 32768,256,256,0, 256,256,256, 0,0,0);
    // MLP layer 2: H = leaky(T@W2+b2)*mask                 (H = buf1)
    gemm_k<0,0,2,0><<<dim3(256,2,1), blk, 0, stream>>>(buf0,       nullptr, W2, b2, buf1,       mk1, 32768,256,256,0, 256,256,256, 0,0,0);
    gemm_k<0,0,2,0><<<dim3(256,2,1), blk, 0, stream>>>(buf0 + SEG, nullptr, W2, b2, buf1 + SEG, mk2, 32768,256,256,0, 256,256,256, 0,0,0);
    // Scores: S[b] = h1[b] @ h2[b]^T                       (S = buf0)
    gemm_k<0,1,0,0><<<dim3(4,4,64), blk, 0, stream>>>(buf1, nullptr, buf1 + SEG, nullptr, buf0, nullptr,
                                                      512,512,256,0, 256,256,512, 512L*256, 512L*256, 512L*512);
    // Softmaxes                                            (O1 = buf2, O2 = buf3)
    softmax_row_k<<<32768, blk, 0, stream>>>(buf0, mk1, mk2, buf2);
    softmax_col_k<<<dim3(8,64), blk, 0, stream>>>(buf0, mk1, mk2, buf3);
    // r1_c = O1 @ h2                                       (RC = buf0)
    gemm_k<0,0,0,0><<<dim3(4,2,64), blk, 0, stream>>>(buf2, nullptr, buf1 + SEG, nullptr, buf0, nullptr,
                                                      512,256,512,0, 512,256,256, 512L*512, 512L*256, 512L*256);
    // r2_c = O2^T @ h1
    gemm_k<1,0,0,0><<<dim3(4,2,64), blk, 0, stream>>>(buf3, nullptr, buf1, nullptr, buf0 + SEG, nullptr,
                                                      512,256,512,0, 512,256,256, 512L*512, 512L*256, 512L*256);
    // Compare layer 1: C1 = leaky([H|RC]@Wc1+bc1)          (C1 = buf2)
    gemm_k<0,0,1,1><<<dim3(256,2,1), blk, 0, stream>>>(buf1,       buf0,       Wc1, bc1, buf2,       nullptr, 32768,256,512,256, 256,256,256, 0,0,0);
    gemm_k<0,0,1,1><<<dim3(256,2,1), blk, 0, stream>>>(buf1 + SEG, buf0 + SEG, Wc1, bc1, buf2 + SEG, nullptr, 32768,256,512,256, 256,256,256, 0,0,0);
    // Compare layer 2: RCMP = leaky(C1@Wc2+bc2)            (RCMP = buf3)
    gemm_k<0,0,1,0><<<dim3(256,2,1), blk, 0, stream>>>(buf2,       nullptr, Wc2, bc2, buf3,       nullptr, 32768,256,256,0, 256,256,256, 0,0,0);
    gemm_k<0,0,1,0><<<dim3(256,2,1), blk, 0, stream>>>(buf2 + SEG, nullptr, Wc2, bc2, buf3 + SEG, nullptr, 32768,256,256,0, 256,256,256, 0,0,0);
    // Masked mean-pool
    pool_k<<<128, blk, 0, stream>>>(buf3, mk1, mk2, out);
}

// Round 3
// 807.565 us; speedup vs baseline: 1.5412x; 1.5412x over previous
//
#include <hip/hip_runtime.h>
#include <math.h>

// InterAttention B=64, L1=L2=512, D=256 — split-bf16 MFMA pipeline.
// Every activation tensor is stored as u32 = (bf16_hi << 16) | bf16_lo, so
// x ~= hi + lo to ~2^-17 relative. GEMMs compute Ahi*Bhi + Ahi*Blo + Alo*Bhi
// on v_mfma_f32_16x16x32_bf16 with fp32 accumulation.
// ws layout: 4 slots of E=16.7M words (67MB) — exactly the footprint of the
// proven fp32 round:  S0: S(fp32) -> O1(pair,in-place) -> C1(pair)
//                     S1: T(pair) -> O2(pair) -> RCMP(fp32)
//                     S2: H(pair)      S3: RC(pair)

using frag  = __attribute__((ext_vector_type(8))) short;  // 8 x bf16
using f32x4 = __attribute__((ext_vector_type(4))) float;

constexpr int  LDK = 40;          // padded bf16 elems per LDS row (80B rows: 2-way banks, 16B-aligned)
constexpr int  KS  = 32;          // K per step == MFMA K
constexpr long E   = 16777216L;   // elems per tensor (65536*256 == 64*512*512)

__device__ __forceinline__ float leaky(float x){ return x > 0.f ? x : 0.01f * x; }

__device__ __forceinline__ unsigned bf16_rne(float f){
    unsigned x = __float_as_uint(f);
    return (x + 0x7fffu + ((x >> 16) & 1u)) >> 16;
}
__device__ __forceinline__ unsigned pack_pair(float v){
    unsigned hi = bf16_rne(v);
    float fhi = __uint_as_float(hi << 16);
    unsigned lo = bf16_rne(v - fhi);
    return (hi << 16) | lo;
}

// AMODE: 0 = pair [M,K] k-contig; 1 = fp32 [M,K] k-contig, row-split (pa=r1, pa2=r2);
//        2 = pair [K,M] (m-contig) scatter-stage
// BMODE: 0 = fp32 [K,N] (n-contig) scatter-stage (weights from d_in);
//        1 = pair [N,K] k-contig; 2 = pair [K,N] (n-contig) scatter-stage
// EPI:   0 = fp32 plain; 1 = pair plain; 2 = pair leaky(v+bias);
//        3 = pair leaky(v+bias)*rowmask(mk1/mk2 row-split); 4 = fp32 leaky(v+bias)
// DUALA: K-concat two pair A sources (k<K1 from pa, else pa2), AMODE0 only.
template<int AMODE, int BMODE, int EPI, int DUALA>
__global__ __launch_bounds__(512, 4)
void gemm_k(const unsigned* __restrict__ pa, const unsigned* __restrict__ pa2,
            const unsigned* __restrict__ pb, const float* __restrict__ bias,
            unsigned* __restrict__ pc,
            const int* __restrict__ mk1, const int* __restrict__ mk2,
            int M, int N, int K, int K1,
            int lda, int ldb, int ldc,
            long sA, long sB, long sC)
{
    __shared__ short As_hi[128 * LDK], As_lo[128 * LDK];
    __shared__ short Bs_hi[128 * LDK], Bs_lo[128 * LDK];

    const int z = blockIdx.z;
    const long aoff = (long)z * sA, boff = (long)z * sB, coff = (long)z * sC;
    const int m0 = blockIdx.x * 128, n0 = blockIdx.y * 128;
    const int tid  = threadIdx.x;
    const int lane = tid & 63;
    const int w    = tid >> 6;
    const int wr = w >> 2, wc = w & 3;           // 2x4 wave grid; wave tile 64x32
    const int lrow = lane & 15, lk = (lane >> 4) * 8;

    f32x4 acc[4][2];
#pragma unroll
    for (int i = 0; i < 4; ++i)
#pragma unroll
        for (int j = 0; j < 2; ++j) acc[i][j] = (f32x4){0.f, 0.f, 0.f, 0.f};

    for (int k0 = 0; k0 < K; k0 += KS) {
        // ---------------- stage A ----------------
        if (AMODE == 0) {
            const int row = tid >> 2, k8 = (tid & 3) * 8;
            const unsigned* base = pa + aoff;
            int kk = k0;
            if (DUALA) { if (k0 >= K1) { base = pa2; kk = k0 - K1; } }
            const unsigned* src = base + (long)(m0 + row) * lda + kk + k8;
            uint4 wa = *(const uint4*)src;
            uint4 wb = *(const uint4*)(src + 4);
            uint4 hs, ls;
            hs.x = __builtin_amdgcn_perm(wa.y, wa.x, 0x07060302u);
            ls.x = __builtin_amdgcn_perm(wa.y, wa.x, 0x05040100u);
            hs.y = __builtin_amdgcn_perm(wa.w, wa.z, 0x07060302u);
            ls.y = __builtin_amdgcn_perm(wa.w, wa.z, 0x05040100u);
            hs.z = __builtin_amdgcn_perm(wb.y, wb.x, 0x07060302u);
            ls.z = __builtin_amdgcn_perm(wb.y, wb.x, 0x05040100u);
            hs.w = __builtin_amdgcn_perm(wb.w, wb.z, 0x07060302u);
            ls.w = __builtin_amdgcn_perm(wb.w, wb.z, 0x05040100u);
            *(uint4*)&As_hi[row * LDK + k8] = hs;
            *(uint4*)&As_lo[row * LDK + k8] = ls;
        } else if (AMODE == 1) {
            const int row = tid >> 2, k8 = (tid & 3) * 8;
            const int gr = m0 + row;
            const float* fb_ = (gr < 32768) ? ((const float*)pa  + (long)gr * lda)
                                            : ((const float*)pa2 + (long)(gr - 32768) * lda);
            const float* src = fb_ + k0 + k8;
            float4 fa = *(const float4*)src, fbv = *(const float4*)(src + 4);
            float f[8] = {fa.x, fa.y, fa.z, fa.w, fbv.x, fbv.y, fbv.z, fbv.w};
            unsigned hi[8], lo[8];
#pragma unroll
            for (int j = 0; j < 8; ++j) {
                hi[j] = bf16_rne(f[j]);
                lo[j] = bf16_rne(f[j] - __uint_as_float(hi[j] << 16));
            }
            uint4 hs = {hi[0] | (hi[1] << 16), hi[2] | (hi[3] << 16), hi[4] | (hi[5] << 16), hi[6] | (hi[7] << 16)};
            uint4 ls = {lo[0] | (lo[1] << 16), lo[2] | (lo[3] << 16), lo[4] | (lo[5] << 16), lo[6] | (lo[7] << 16)};
            *(uint4*)&As_hi[row * LDK + k8] = hs;
            *(uint4*)&As_lo[row * LDK + k8] = ls;
        } else { // AMODE 2: pair [K,M] scatter (O2)
            if (tid < 256) {
                const int k2 = ((tid >> 4) & 15) * 2, m8 = (tid & 15) * 8;
                const unsigned* s0 = pa + aoff + (long)(k0 + k2) * lda + m0 + m8;
                const unsigned* s1 = s0 + lda;
                uint4 a0 = *(const uint4*)s0, a1 = *(const uint4*)(s0 + 4);
                uint4 b0 = *(const uint4*)s1, b1 = *(const uint4*)(s1 + 4);
                unsigned wk[8]  = {a0.x, a0.y, a0.z, a0.w, a1.x, a1.y, a1.z, a1.w};
                unsigned wk1[8] = {b0.x, b0.y, b0.z, b0.w, b1.x, b1.y, b1.z, b1.w};
#pragma unroll
                for (int i = 0; i < 8; ++i) {
                    unsigned hw = __builtin_amdgcn_perm(wk1[i], wk[i], 0x07060302u);
                    unsigned lw = __builtin_amdgcn_perm(wk1[i], wk[i], 0x05040100u);
                    *(unsigned*)&As_hi[(m8 + i) * LDK + k2] = hw;
                    *(unsigned*)&As_lo[(m8 + i) * LDK + k2] = lw;
                }
            }
        }
        // ---------------- stage B ----------------
        if (BMODE == 1) {
            const int row = tid >> 2, k8 = (tid & 3) * 8;
            const unsigned* src = pb + boff + (long)(n0 + row) * ldb + k0 + k8;
            uint4 wa = *(const uint4*)src;
            uint4 wb = *(const uint4*)(src + 4);
            uint4 hs, ls;
            hs.x = __builtin_amdgcn_perm(wa.y, wa.x, 0x07060302u);
            ls.x = __builtin_amdgcn_perm(wa.y, wa.x, 0x05040100u);
            hs.y = __builtin_amdgcn_perm(wa.w, wa.z, 0x07060302u);
            ls.y = __builtin_amdgcn_perm(wa.w, wa.z, 0x05040100u);
            hs.z = __builtin_amdgcn_perm(wb.y, wb.x, 0x07060302u);
            ls.z = __builtin_amdgcn_perm(wb.y, wb.x, 0x05040100u);
            hs.w = __builtin_amdgcn_perm(wb.w, wb.z, 0x07060302u);
            ls.w = __builtin_amdgcn_perm(wb.w, wb.z, 0x05040100u);
            *(uint4*)&Bs_hi[row * LDK + k8] = hs;
            *(uint4*)&Bs_lo[row * LDK + k8] = ls;
        } else if (BMODE == 0) { // fp32 [K,N] scatter (weights)
            if (tid < 256) {
                const int k2 = ((tid >> 4) & 15) * 2, n8 = (tid & 15) * 8;
                const float* s0 = (const float*)pb + boff + (long)(k0 + k2) * ldb + n0 + n8;
                const float* s1 = s0 + ldb;
                float4 a0 = *(const float4*)s0, a1 = *(const float4*)(s0 + 4);
                float4 b0 = *(const float4*)s1, b1 = *(const float4*)(s1 + 4);
                float f0[8] = {a0.x, a0.y, a0.z, a0.w, a1.x, a1.y, a1.z, a1.w};
                float f1[8] = {b0.x, b0.y, b0.z, b0.w, b1.x, b1.y, b1.z, b1.w};
#pragma unroll
                for (int i = 0; i < 8; ++i) {
                    unsigned h0 = bf16_rne(f0[i]);
                    unsigned l0 = bf16_rne(f0[i] - __uint_as_float(h0 << 16));
                    unsigned h1 = bf16_rne(f1[i]);
                    unsigned l1 = bf16_rne(f1[i] - __uint_as_float(h1 << 16));
                    *(unsigned*)&Bs_hi[(n8 + i) * LDK + k2] = h0 | (h1 << 16);
                    *(unsigned*)&Bs_lo[(n8 + i) * LDK + k2] = l0 | (l1 << 16);
                }
            }
        } else { // BMODE 2: pair [K,N] scatter (h as B operand)
            if (tid < 256) {
                const int k2 = ((tid >> 4) & 15) * 2, n8 = (tid & 15) * 8;
                const unsigned* s0 = pb + boff + (long)(k0 + k2) * ldb + n0 + n8;
                const unsigned* s1 = s0 + ldb;
                uint4 a0 = *(const uint4*)s0, a1 = *(const uint4*)(s0 + 4);
                uint4 b0 = *(const uint4*)s1, b1 = *(const uint4*)(s1 + 4);
                unsigned wk[8]  = {a0.x, a0.y, a0.z, a0.w, a1.x, a1.y, a1.z, a1.w};
                unsigned wk1[8] = {b0.x, b0.y, b0.z, b0.w, b1.x, b1.y, b1.z, b1.w};
#pragma unroll
                for (int i = 0; i < 8; ++i) {
                    unsigned hw = __builtin_amdgcn_perm(wk1[i], wk[i], 0x07060302u);
                    unsigned lw = __builtin_amdgcn_perm(wk1[i], wk[i], 0x05040100u);
                    *(unsigned*)&Bs_hi[(n8 + i) * LDK + k2] = hw;
                    *(unsigned*)&Bs_lo[(n8 + i) * LDK + k2] = lw;
                }
            }
        }
        __syncthreads();

        // ---------------- MFMA ----------------
        frag ah[4], al[4], bh[2], bl[2];
#pragma unroll
        for (int mi = 0; mi < 4; ++mi) {
            const int r = (wr * 64 + mi * 16 + lrow) * LDK + lk;
            ah[mi] = *(const frag*)&As_hi[r];
            al[mi] = *(const frag*)&As_lo[r];
        }
#pragma unroll
        for (int ni = 0; ni < 2; ++ni) {
            const int r = (wc * 32 + ni * 16 + lrow) * LDK + lk;
            bh[ni] = *(const frag*)&Bs_hi[r];
            bl[ni] = *(const frag*)&Bs_lo[r];
        }
#pragma unroll
        for (int mi = 0; mi < 4; ++mi)
#pragma unroll
            for (int ni = 0; ni < 2; ++ni) {
                acc[mi][ni] = __builtin_amdgcn_mfma_f32_16x16x32_bf16(ah[mi], bh[ni], acc[mi][ni], 0, 0, 0);
                acc[mi][ni] = __builtin_amdgcn_mfma_f32_16x16x32_bf16(ah[mi], bl[ni], acc[mi][ni], 0, 0, 0);
                acc[mi][ni] = __builtin_amdgcn_mfma_f32_16x16x32_bf16(al[mi], bh[ni], acc[mi][ni], 0, 0, 0);
            }
        __syncthreads();
    }

    // ---------------- epilogue ----------------
    float bvv[2];
    if (EPI == 2 || EPI == 3 || EPI == 4) {
#pragma unroll
        for (int ni = 0; ni < 2; ++ni) bvv[ni] = bias[n0 + wc * 32 + ni * 16 + lrow];
    }
#pragma unroll
    for (int mi = 0; mi < 4; ++mi)
#pragma unroll
        for (int ni = 0; ni < 2; ++ni) {
            const int col = n0 + wc * 32 + ni * 16 + lrow;
#pragma unroll
            for (int r = 0; r < 4; ++r) {
                const int row = m0 + wr * 64 + mi * 16 + (lane >> 4) * 4 + r;
                float v = acc[mi][ni][r];
                if (EPI == 2 || EPI == 3 || EPI == 4) v = leaky(v + bvv[ni]);
                if (EPI == 3) v *= (float)(row < 32768 ? mk1[row] : mk2[row - 32768]);
                const long off = coff + (long)row * ldc + col;
                if (EPI == 0 || EPI == 4) ((float*)pc)[off] = v;
                else                      pc[off] = pack_pair(v);
            }
        }
}

// One block per (b,l) row of S (fp32); masked softmax over 512 cols -> pair words.
// May run IN-PLACE (O aliases S): all reads precede all writes.
__global__ __launch_bounds__(256)
void softmax_row_k(const unsigned* S, const int* m1, const int* m2, unsigned* O)
{
    __shared__ float red[4];
    const int gr = blockIdx.x;
    const int b = gr >> 9;
    const int l = gr & 511;
    const unsigned* srow = S + (long)gr * 512;
    unsigned* orow = O + (long)gr * 512;
    const int tid = threadIdx.x;
    const int c0 = tid, c1 = tid + 256;
    const int rowvalid = m1[(long)b * 512 + l];
    const int* m2b = m2 + (long)b * 512;
    const int a0 = m2b[c0], a1 = m2b[c1];
    const float v0 = __uint_as_float(srow[c0]), v1 = __uint_as_float(srow[c1]);
    float x = fmaxf(a0 ? v0 : -3e38f, a1 ? v1 : -3e38f);
#pragma unroll
    for (int o = 32; o; o >>= 1) x = fmaxf(x, __shfl_xor(x, o));
    if ((tid & 63) == 0) red[tid >> 6] = x;
    __syncthreads();
    const float mx = fmaxf(fmaxf(red[0], red[1]), fmaxf(red[2], red[3]));
    __syncthreads();
    if (!rowvalid || mx < -1e30f) { orow[c0] = 0u; orow[c1] = 0u; return; }
    float p0 = a0 ? expf(v0 - mx) : 0.f;
    float p1 = a1 ? expf(v1 - mx) : 0.f;
    float s = p0 + p1;
#pragma unroll
    for (int o = 32; o; o >>= 1) s += __shfl_xor(s, o);
    if ((tid & 63) == 0) red[tid >> 6] = s;
    __syncthreads();
    const float inv = 1.f / (red[0] + red[1] + red[2] + red[3]);
    orow[c0] = pack_pair(p0 * inv);
    orow[c1] = pack_pair(p1 * inv);
}

// One block per (b, 64-col tile): online column softmax (axis=l) -> pair words.
__global__ __launch_bounds__(256)
void softmax_col_k(const unsigned* __restrict__ S, const int* __restrict__ m1,
                   const int* __restrict__ m2, unsigned* __restrict__ O)
{
    __shared__ float smM[4][64], smS[4][64], colM[64], colI[64];
    const int b = blockIdx.y;
    const int c0 = blockIdx.x * 64;
    const int tid = threadIdx.x;
    const int c = tid & 63, rq = tid >> 6;
    const int* m1b = m1 + (long)b * 512;
    const int* m2b = m2 + (long)b * 512;
    const unsigned* Sb = S + (long)b * 512 * 512;
    unsigned* Ob = O + (long)b * 512 * 512;
    float mt = -3e38f, st = 0.f;
    for (int r = rq; r < 512; r += 4) {
        if (m1b[r]) {
            float v = __uint_as_float(Sb[(long)r * 512 + c0 + c]);
            if (v <= mt) st += expf(v - mt);
            else { st = st * expf(mt - v) + 1.f; mt = v; }
        }
    }
    smM[rq][c] = mt; smS[rq][c] = st;
    __syncthreads();
    if (rq == 0) {
        float M = fmaxf(fmaxf(smM[0][c], smM[1][c]), fmaxf(smM[2][c], smM[3][c]));
        float ssum = 0.f;
#pragma unroll
        for (int i = 0; i < 4; ++i) {
            float mi = smM[i][c];
            if (mi > -1e30f) ssum += smS[i][c] * expf(mi - M);
        }
        colM[c] = M;
        colI[c] = (ssum > 0.f) ? 1.f / ssum : 0.f;
    }
    __syncthreads();
    const float M = colM[c], inv = colI[c];
    const int ac = m2b[c0 + c];
    for (int r = rq; r < 512; r += 4) {
        float o = 0.f;
        if (ac && m1b[r] && inv != 0.f)
            o = expf(__uint_as_float(Sb[(long)r * 512 + c0 + c]) - M) * inv;
        Ob[(long)r * 512 + c0 + c] = pack_pair(o);
    }
}

// One block per (seg,b): out[b,:] = sum_l mask*RCMP[l,:] / count   (RCMP fp32)
__global__ __launch_bounds__(256)
void pool_k(const float* __restrict__ RC, const int* __restrict__ m1,
            const int* __restrict__ m2, float* __restrict__ out)
{
    const int seg = blockIdx.x >> 6, b = blockIdx.x & 63;
    const int* mb = (seg ? m2 : m1) + (long)b * 512;
    const float* base = RC + ((long)seg * 32768 + (long)b * 512) * 256;
    const int n = threadIdx.x;
    float acc = 0.f; int cnt = 0;
    for (int l = 0; l < 512; ++l) {
        int m = mb[l];
        if (m) { cnt++; acc += base[(long)l * 256 + n]; }
    }
    out[((long)seg * 64 + b) * 256 + n] = acc / (float)cnt;
}

extern "C" void kernel_launch(void* const* d_in, const int* in_sizes, int n_in,
                              void* d_out, int out_size, void* d_ws, size_t ws_size,
                              hipStream_t stream)
{
    const float* r1  = (const float*)d_in[0];
    const float* r2  = (const float*)d_in[1];
    const int*   mk1 = (const int*)d_in[2];
    const int*   mk2 = (const int*)d_in[3];
    const float* W1  = (const float*)d_in[4];
    const float* b1  = (const float*)d_in[5];
    const float* W2  = (const float*)d_in[6];
    const float* b2  = (const float*)d_in[7];
    const float* Wc1 = (const float*)d_in[8];
    const float* bc1 = (const float*)d_in[9];
    const float* Wc2 = (const float*)d_in[10];
    const float* bc2 = (const float*)d_in[11];
    float* out = (float*)d_out;

    unsigned* S0 = (unsigned*)d_ws;
    unsigned* S1 = S0 + E;
    unsigned* S2 = S0 + 2 * E;
    unsigned* S3 = S0 + 3 * E;
    const long H2OFF = 32768L * 256;    // word offset of h2 rows inside H

    dim3 blk(512), sblk(256);

    // mlp1: T(S1) = leaky(X@W1+b1), X = [r1;r2] fp32 row-split
    gemm_k<1,0,2,0><<<dim3(512,2,1), blk, 0, stream>>>(
        (const unsigned*)r1, (const unsigned*)r2, (const unsigned*)W1, b1, S1,
        nullptr, nullptr, 65536,256,256,0, 256,256,256, 0,0,0);
    // mlp2: H(S2) = leaky(T@W2+b2) * rowmask
    gemm_k<0,0,3,0><<<dim3(512,2,1), blk, 0, stream>>>(
        S1, nullptr, (const unsigned*)W2, b2, S2,
        mk1, mk2, 65536,256,256,0, 256,256,256, 0,0,0);
    // scores: S(S0 fp32)[b] = h1[b] @ h2[b]^T
    gemm_k<0,1,0,0><<<dim3(4,4,64), blk, 0, stream>>>(
        S2, nullptr, S2 + H2OFF, nullptr, S0,
        nullptr, nullptr, 512,512,256,0, 256,256,512, 131072,131072,262144);
    // column softmax first (reads S), then row softmax IN-PLACE over S -> O1
    softmax_col_k<<<dim3(8,64), sblk, 0, stream>>>(S0, mk1, mk2, S1);   // O2 = S1 (T dead)
    softmax_row_k<<<32768, sblk, 0, stream>>>(S0, mk1, mk2, S0);        // O1 = S0 in-place
    // rc1: RC(S3)[0:32768] = O1 @ h2
    gemm_k<0,2,1,0><<<dim3(4,2,64), blk, 0, stream>>>(
        S0, nullptr, S2 + H2OFF, nullptr, S3,
        nullptr, nullptr, 512,256,512,0, 512,256,256, 262144,131072,131072);
    // rc2: RC(S3)[32768:] = O2^T @ h1
    gemm_k<2,2,1,0><<<dim3(4,2,64), blk, 0, stream>>>(
        S1, nullptr, S2, nullptr, S3 + H2OFF,
        nullptr, nullptr, 512,256,512,0, 512,256,256, 262144,131072,131072);
    // cmp1: C1(S0) = leaky([H|RC] @ Wc1 + bc1)   (K-concat via DUALA)
    gemm_k<0,0,2,1><<<dim3(512,2,1), blk, 0, stream>>>(
        S2, S3, (const unsigned*)Wc1, bc1, S0,
        nullptr, nullptr, 65536,256,512,256, 256,256,256, 0,0,0);
    // cmp2: RCMP(S1 fp32) = leaky(C1 @ Wc2 + bc2)
    gemm_k<0,0,4,0><<<dim3(512,2,1), blk, 0, stream>>>(
        S0, nullptr, (const unsigned*)Wc2, bc2, S1,
        nullptr, nullptr, 65536,256,256,0, 256,256,256, 0,0,0);
    // masked mean-pool
    pool_k<<<128, sblk, 0, stream>>>((const float*)S1, mk1, mk2, out);
}

// Round 4
// 633.290 us; speedup vs baseline: 1.9654x; 1.2752x over previous
//
#include <hip/hip_runtime.h>
#include <math.h>

// InterAttention B=64, L1=L2=512, D=256 — split-bf16 MFMA pipeline.
// Activations stored as u32 = (bf16_hi << 16) | bf16_lo; GEMMs compute
// Ahi*Bhi + Ahi*Blo + Alo*Bhi on v_mfma_f32_16x16x32_bf16, fp32 accum.
// ws: 4 slots of E words (67MB):
//   S0: S(fp32) -> O1(pair,in-place) -> C1(pair)
//   S1: T(pair) -> O2(pair) -> RCMP(fp32)
//   S2: H(pair) -> pool partials          S3: RC(pair)

using frag  = __attribute__((ext_vector_type(8))) short;  // 8 x bf16
using f32x4 = __attribute__((ext_vector_type(4))) float;

constexpr int  LDK = 40;          // padded bf16 elems per LDS row
constexpr int  KS  = 32;          // K per step == MFMA K
constexpr long E   = 16777216L;   // elems per tensor (65536*256 == 64*512*512)

__device__ __forceinline__ float leaky(float x){ return x > 0.f ? x : 0.01f * x; }

__device__ __forceinline__ unsigned bf16_rne(float f){
    unsigned x = __float_as_uint(f);
    return (x + 0x7fffu + ((x >> 16) & 1u)) >> 16;
}
__device__ __forceinline__ unsigned pack_pair(float v){
    unsigned hi = bf16_rne(v);
    float fhi = __uint_as_float(hi << 16);
    unsigned lo = bf16_rne(v - fhi);
    return (hi << 16) | lo;
}

// AMODE: 0 = pair [M,K] k-contig; 1 = fp32 [M,K] k-contig, row-split (pa=r1, pa2=r2);
//        2 = pair [K,M] (m-contig) scatter-stage
// BMODE: 0 = fp32 [K,N] (n-contig) scatter; 1 = pair [N,K] k-contig; 2 = pair [K,N] scatter
// EPI:   0 fp32 plain; 1 pair plain; 2 pair leaky(v+bias); 3 pair leaky(v+bias)*rowmask; 4 fp32 leaky(v+bias)
// DUALA: K-concat two pair A sources (k<K1 from pa, else pa2), AMODE0 only.
template<int AMODE, int BMODE, int EPI, int DUALA>
__global__ __launch_bounds__(512, 4)
void gemm_k(const unsigned* __restrict__ pa, const unsigned* __restrict__ pa2,
            const unsigned* __restrict__ pb, const float* __restrict__ bias,
            unsigned* __restrict__ pc,
            const int* __restrict__ mk1, const int* __restrict__ mk2,
            int M, int N, int K, int K1,
            int lda, int ldb, int ldc,
            long sA, long sB, long sC)
{
    __shared__ short As_hi[128 * LDK], As_lo[128 * LDK];
    __shared__ short Bs_hi[128 * LDK], Bs_lo[128 * LDK];

    const int z = blockIdx.z;
    const long aoff = (long)z * sA, boff = (long)z * sB, coff = (long)z * sC;
    const int m0 = blockIdx.x * 128, n0 = blockIdx.y * 128;
    const int tid  = threadIdx.x;
    const int lane = tid & 63;
    const int w    = tid >> 6;
    const int wr = w >> 2, wc = w & 3;           // 2x4 wave grid; wave tile 64x32
    const int lrow = lane & 15, lk = (lane >> 4) * 8;

    f32x4 acc[4][2];
#pragma unroll
    for (int i = 0; i < 4; ++i)
#pragma unroll
        for (int j = 0; j < 2; ++j) acc[i][j] = (f32x4){0.f, 0.f, 0.f, 0.f};

    for (int k0 = 0; k0 < K; k0 += KS) {
        // ---------------- stage A ----------------
        if (AMODE == 0) {
            const int row = tid >> 2, k8 = (tid & 3) * 8;
            const unsigned* base = pa + aoff;
            int kk = k0;
            if (DUALA) { if (k0 >= K1) { base = pa2; kk = k0 - K1; } }
            const unsigned* src = base + (long)(m0 + row) * lda + kk + k8;
            uint4 wa = *(const uint4*)src;
            uint4 wb = *(const uint4*)(src + 4);
            uint4 hs, ls;
            hs.x = __builtin_amdgcn_perm(wa.y, wa.x, 0x07060302u);
            ls.x = __builtin_amdgcn_perm(wa.y, wa.x, 0x05040100u);
            hs.y = __builtin_amdgcn_perm(wa.w, wa.z, 0x07060302u);
            ls.y = __builtin_amdgcn_perm(wa.w, wa.z, 0x05040100u);
            hs.z = __builtin_amdgcn_perm(wb.y, wb.x, 0x07060302u);
            ls.z = __builtin_amdgcn_perm(wb.y, wb.x, 0x05040100u);
            hs.w = __builtin_amdgcn_perm(wb.w, wb.z, 0x07060302u);
            ls.w = __builtin_amdgcn_perm(wb.w, wb.z, 0x05040100u);
            *(uint4*)&As_hi[row * LDK + k8] = hs;
            *(uint4*)&As_lo[row * LDK + k8] = ls;
        } else if (AMODE == 1) {
            const int row = tid >> 2, k8 = (tid & 3) * 8;
            const int gr = m0 + row;
            const float* fb_ = (gr < 32768) ? ((const float*)pa  + (long)gr * lda)
                                            : ((const float*)pa2 + (long)(gr - 32768) * lda);
            const float* src = fb_ + k0 + k8;
            float4 fa = *(const float4*)src, fbv = *(const float4*)(src + 4);
            float f[8] = {fa.x, fa.y, fa.z, fa.w, fbv.x, fbv.y, fbv.z, fbv.w};
            unsigned hi[8], lo[8];
#pragma unroll
            for (int j = 0; j < 8; ++j) {
                hi[j] = bf16_rne(f[j]);
                lo[j] = bf16_rne(f[j] - __uint_as_float(hi[j] << 16));
            }
            uint4 hs = {hi[0] | (hi[1] << 16), hi[2] | (hi[3] << 16), hi[4] | (hi[5] << 16), hi[6] | (hi[7] << 16)};
            uint4 ls = {lo[0] | (lo[1] << 16), lo[2] | (lo[3] << 16), lo[4] | (lo[5] << 16), lo[6] | (lo[7] << 16)};
            *(uint4*)&As_hi[row * LDK + k8] = hs;
            *(uint4*)&As_lo[row * LDK + k8] = ls;
        } else { // AMODE 2: pair [K,M] scatter (O2)
            if (tid < 256) {
                const int k2 = ((tid >> 4) & 15) * 2, m8 = (tid & 15) * 8;
                const unsigned* s0 = pa + aoff + (long)(k0 + k2) * lda + m0 + m8;
                const unsigned* s1 = s0 + lda;
                uint4 a0 = *(const uint4*)s0, a1 = *(const uint4*)(s0 + 4);
                uint4 b0 = *(const uint4*)s1, b1 = *(const uint4*)(s1 + 4);
                unsigned wk[8]  = {a0.x, a0.y, a0.z, a0.w, a1.x, a1.y, a1.z, a1.w};
                unsigned wk1[8] = {b0.x, b0.y, b0.z, b0.w, b1.x, b1.y, b1.z, b1.w};
#pragma unroll
                for (int i = 0; i < 8; ++i) {
                    unsigned hw = __builtin_amdgcn_perm(wk1[i], wk[i], 0x07060302u);
                    unsigned lw = __builtin_amdgcn_perm(wk1[i], wk[i], 0x05040100u);
                    *(unsigned*)&As_hi[(m8 + i) * LDK + k2] = hw;
                    *(unsigned*)&As_lo[(m8 + i) * LDK + k2] = lw;
                }
            }
        }
        // ---------------- stage B ----------------
        if (BMODE == 1) {
            const int row = tid >> 2, k8 = (tid & 3) * 8;
            const unsigned* src = pb + boff + (long)(n0 + row) * ldb + k0 + k8;
            uint4 wa = *(const uint4*)src;
            uint4 wb = *(const uint4*)(src + 4);
            uint4 hs, ls;
            hs.x = __builtin_amdgcn_perm(wa.y, wa.x, 0x07060302u);
            ls.x = __builtin_amdgcn_perm(wa.y, wa.x, 0x05040100u);
            hs.y = __builtin_amdgcn_perm(wa.w, wa.z, 0x07060302u);
            ls.y = __builtin_amdgcn_perm(wa.w, wa.z, 0x05040100u);
            hs.z = __builtin_amdgcn_perm(wb.y, wb.x, 0x07060302u);
            ls.z = __builtin_amdgcn_perm(wb.y, wb.x, 0x05040100u);
            hs.w = __builtin_amdgcn_perm(wb.w, wb.z, 0x07060302u);
            ls.w = __builtin_amdgcn_perm(wb.w, wb.z, 0x05040100u);
            *(uint4*)&Bs_hi[row * LDK + k8] = hs;
            *(uint4*)&Bs_lo[row * LDK + k8] = ls;
        } else if (BMODE == 0) { // fp32 [K,N] scatter (weights)
            if (tid < 256) {
                const int k2 = ((tid >> 4) & 15) * 2, n8 = (tid & 15) * 8;
                const float* s0 = (const float*)pb + boff + (long)(k0 + k2) * ldb + n0 + n8;
                const float* s1 = s0 + ldb;
                float4 a0 = *(const float4*)s0, a1 = *(const float4*)(s0 + 4);
                float4 b0 = *(const float4*)s1, b1 = *(const float4*)(s1 + 4);
                float f0[8] = {a0.x, a0.y, a0.z, a0.w, a1.x, a1.y, a1.z, a1.w};
                float f1[8] = {b0.x, b0.y, b0.z, b0.w, b1.x, b1.y, b1.z, b1.w};
#pragma unroll
                for (int i = 0; i < 8; ++i) {
                    unsigned h0 = bf16_rne(f0[i]);
                    unsigned l0 = bf16_rne(f0[i] - __uint_as_float(h0 << 16));
                    unsigned h1 = bf16_rne(f1[i]);
                    unsigned l1 = bf16_rne(f1[i] - __uint_as_float(h1 << 16));
                    *(unsigned*)&Bs_hi[(n8 + i) * LDK + k2] = h0 | (h1 << 16);
                    *(unsigned*)&Bs_lo[(n8 + i) * LDK + k2] = l0 | (l1 << 16);
                }
            }
        } else { // BMODE 2: pair [K,N] scatter (h as B operand)
            if (tid < 256) {
                const int k2 = ((tid >> 4) & 15) * 2, n8 = (tid & 15) * 8;
                const unsigned* s0 = pb + boff + (long)(k0 + k2) * ldb + n0 + n8;
                const unsigned* s1 = s0 + ldb;
                uint4 a0 = *(const uint4*)s0, a1 = *(const uint4*)(s0 + 4);
                uint4 b0 = *(const uint4*)s1, b1 = *(const uint4*)(s1 + 4);
                unsigned wk[8]  = {a0.x, a0.y, a0.z, a0.w, a1.x, a1.y, a1.z, a1.w};
                unsigned wk1[8] = {b0.x, b0.y, b0.z, b0.w, b1.x, b1.y, b1.z, b1.w};
#pragma unroll
                for (int i = 0; i < 8; ++i) {
                    unsigned hw = __builtin_amdgcn_perm(wk1[i], wk[i], 0x07060302u);
                    unsigned lw = __builtin_amdgcn_perm(wk1[i], wk[i], 0x05040100u);
                    *(unsigned*)&Bs_hi[(n8 + i) * LDK + k2] = hw;
                    *(unsigned*)&Bs_lo[(n8 + i) * LDK + k2] = lw;
                }
            }
        }
        __syncthreads();

        // ---------------- MFMA ----------------
        frag ah[4], al[4], bh[2], bl[2];
#pragma unroll
        for (int mi = 0; mi < 4; ++mi) {
            const int r = (wr * 64 + mi * 16 + lrow) * LDK + lk;
            ah[mi] = *(const frag*)&As_hi[r];
            al[mi] = *(const frag*)&As_lo[r];
        }
#pragma unroll
        for (int ni = 0; ni < 2; ++ni) {
            const int r = (wc * 32 + ni * 16 + lrow) * LDK + lk;
            bh[ni] = *(const frag*)&Bs_hi[r];
            bl[ni] = *(const frag*)&Bs_lo[r];
        }
#pragma unroll
        for (int mi = 0; mi < 4; ++mi)
#pragma unroll
            for (int ni = 0; ni < 2; ++ni) {
                acc[mi][ni] = __builtin_amdgcn_mfma_f32_16x16x32_bf16(ah[mi], bh[ni], acc[mi][ni], 0, 0, 0);
                acc[mi][ni] = __builtin_amdgcn_mfma_f32_16x16x32_bf16(ah[mi], bl[ni], acc[mi][ni], 0, 0, 0);
                acc[mi][ni] = __builtin_amdgcn_mfma_f32_16x16x32_bf16(al[mi], bh[ni], acc[mi][ni], 0, 0, 0);
            }
        __syncthreads();
    }

    // ---------------- epilogue ----------------
    float bvv[2];
    if (EPI == 2 || EPI == 3 || EPI == 4) {
#pragma unroll
        for (int ni = 0; ni < 2; ++ni) bvv[ni] = bias[n0 + wc * 32 + ni * 16 + lrow];
    }
#pragma unroll
    for (int mi = 0; mi < 4; ++mi)
#pragma unroll
        for (int ni = 0; ni < 2; ++ni) {
            const int col = n0 + wc * 32 + ni * 16 + lrow;
#pragma unroll
            for (int r = 0; r < 4; ++r) {
                const int row = m0 + wr * 64 + mi * 16 + (lane >> 4) * 4 + r;
                float v = acc[mi][ni][r];
                if (EPI == 2 || EPI == 3 || EPI == 4) v = leaky(v + bvv[ni]);
                if (EPI == 3) v *= (float)(row < 32768 ? mk1[row] : mk2[row - 32768]);
                const long off = coff + (long)row * ldc + col;
                if (EPI == 0 || EPI == 4) ((float*)pc)[off] = v;
                else                      pc[off] = pack_pair(v);
            }
        }
}

// One WAVE per row of S (fp32); masked softmax over 512 cols -> pair words.
// In-place safe: each lane reads only the 8 cols it later writes.
__global__ __launch_bounds__(256)
void softmax_row_k(const unsigned* __restrict__ S, const int* __restrict__ m1,
                   const int* __restrict__ m2, unsigned* __restrict__ O)
{
    const int tid = threadIdx.x;
    const int wid = tid >> 6, lane = tid & 63;
    const int gr = blockIdx.x * 4 + wid;            // 0..32767
    const int b = gr >> 9, l = gr & 511;
    const unsigned* srow = S + (long)gr * 512;
    unsigned* orow = O + (long)gr * 512;
    const int rowvalid = m1[(long)b * 512 + l];
    const int* m2b = m2 + (long)b * 512;
    const int c8 = lane * 8;
    int4 ma = *(const int4*)(m2b + c8);
    int4 mb_ = *(const int4*)(m2b + c8 + 4);
    uint4 va = *(const uint4*)(srow + c8);
    uint4 vb = *(const uint4*)(srow + c8 + 4);
    float v[8] = {__uint_as_float(va.x), __uint_as_float(va.y), __uint_as_float(va.z), __uint_as_float(va.w),
                  __uint_as_float(vb.x), __uint_as_float(vb.y), __uint_as_float(vb.z), __uint_as_float(vb.w)};
    int mk[8] = {ma.x, ma.y, ma.z, ma.w, mb_.x, mb_.y, mb_.z, mb_.w};
    float mx = -3e38f;
#pragma unroll
    for (int j = 0; j < 8; ++j) if (mk[j]) mx = fmaxf(mx, v[j]);
#pragma unroll
    for (int o = 32; o; o >>= 1) mx = fmaxf(mx, __shfl_xor(mx, o));
    if (!rowvalid || mx < -1e30f) {
        uint4 zz = {0u, 0u, 0u, 0u};
        *(uint4*)(orow + c8) = zz; *(uint4*)(orow + c8 + 4) = zz;
        return;
    }
    float e[8]; float s = 0.f;
#pragma unroll
    for (int j = 0; j < 8; ++j) { e[j] = mk[j] ? __expf(v[j] - mx) : 0.f; s += e[j]; }
#pragma unroll
    for (int o = 32; o; o >>= 1) s += __shfl_xor(s, o);
    const float inv = 1.f / s;
    uint4 oa, ob;
    oa.x = pack_pair(e[0] * inv); oa.y = pack_pair(e[1] * inv);
    oa.z = pack_pair(e[2] * inv); oa.w = pack_pair(e[3] * inv);
    ob.x = pack_pair(e[4] * inv); ob.y = pack_pair(e[5] * inv);
    ob.z = pack_pair(e[6] * inv); ob.w = pack_pair(e[7] * inv);
    *(uint4*)(orow + c8) = oa;
    *(uint4*)(orow + c8 + 4) = ob;
}

// Column softmax, register-resident: block = 1024 thr (16 row-groups x 64 cols),
// one (b, 64-col tile) per block. Single S read, independent __expf.
__global__ __launch_bounds__(1024)
void softmax_col_k(const unsigned* __restrict__ S, const int* __restrict__ m1,
                   const int* __restrict__ m2, unsigned* __restrict__ O)
{
    __shared__ float red[16][64];
    __shared__ int m1s[512];
    const int b = blockIdx.y;
    const int c0 = blockIdx.x * 64;
    const int tid = threadIdx.x;
    const int c = tid & 63, rq = tid >> 6;          // rq in 0..15
    if (tid < 512) m1s[tid] = m1[(long)b * 512 + tid];
    const int ac = m2[(long)b * 512 + c0 + c];
    const unsigned* Sb = S + (long)b * 512 * 512 + c0 + c;
    unsigned* Ob = O + (long)b * 512 * 512 + c0 + c;
    __syncthreads();

    float v[32];
#pragma unroll
    for (int g = 0; g < 32; ++g) {
        const int r = g * 16 + rq;
        float val = __uint_as_float(Sb[(long)r * 512]);
        v[g] = m1s[r] ? val : -3e38f;
    }
    float mx = -3e38f;
#pragma unroll
    for (int g = 0; g < 32; ++g) mx = fmaxf(mx, v[g]);
    red[rq][c] = mx;
    __syncthreads();
    float M = -3e38f;
#pragma unroll
    for (int i = 0; i < 16; ++i) M = fmaxf(M, red[i][c]);
    __syncthreads();
    float s = 0.f;
#pragma unroll
    for (int g = 0; g < 32; ++g) {
        float e = (v[g] > -1e30f) ? __expf(v[g] - M) : 0.f;
        v[g] = e;
        s += e;
    }
    red[rq][c] = s;
    __syncthreads();
    s = 0.f;
#pragma unroll
    for (int i = 0; i < 16; ++i) s += red[i][c];
    const float inv = (ac && s > 0.f) ? 1.f / s : 0.f;
#pragma unroll
    for (int g = 0; g < 32; ++g) {
        const int r = g * 16 + rq;
        Ob[(long)r * 512] = pack_pair(v[g] * inv);
    }
}

// pool phase 1: partial masked sums over 64-row strips. part[(seg*64+b)*8+rs][n]
__global__ __launch_bounds__(256)
void pool_part_k(const float* __restrict__ RC, const int* __restrict__ m1,
                 const int* __restrict__ m2, float* __restrict__ part)
{
    const int rs = blockIdx.x, b = blockIdx.y, seg = blockIdx.z;
    const int* mb = (seg ? m2 : m1) + (long)b * 512;
    const float* base = RC + ((long)seg * 32768 + (long)b * 512) * 256;
    const int n = threadIdx.x;
    float acc = 0.f;
    for (int l = rs * 64; l < rs * 64 + 64; ++l)
        if (mb[l]) acc += base[(long)l * 256 + n];
    part[(((long)seg * 64 + b) * 8 + rs) * 256 + n] = acc;
}

// pool phase 2: sum 8 partials, divide by mask count.
__global__ __launch_bounds__(256)
void pool_red_k(const float* __restrict__ part, const int* __restrict__ m1,
                const int* __restrict__ m2, float* __restrict__ out)
{
    __shared__ float cr[256];
    const int g = blockIdx.x;                  // seg*64 + b
    const int seg = g >> 6, b = g & 63;
    const int n = threadIdx.x;
    const int* mb = (seg ? m2 : m1) + (long)b * 512;
    float s = 0.f;
#pragma unroll
    for (int i = 0; i < 8; ++i) s += part[((long)g * 8 + i) * 256 + n];
    float cpart = (float)(mb[n] + mb[n + 256]);
    cr[n] = cpart;
    __syncthreads();
    for (int o = 128; o; o >>= 1) { if (n < o) cr[n] += cr[n + o]; __syncthreads(); }
    out[(long)g * 256 + n] = s / cr[0];
}

extern "C" void kernel_launch(void* const* d_in, const int* in_sizes, int n_in,
                              void* d_out, int out_size, void* d_ws, size_t ws_size,
                              hipStream_t stream)
{
    const float* r1  = (const float*)d_in[0];
    const float* r2  = (const float*)d_in[1];
    const int*   mk1 = (const int*)d_in[2];
    const int*   mk2 = (const int*)d_in[3];
    const float* W1  = (const float*)d_in[4];
    const float* b1  = (const float*)d_in[5];
    const float* W2  = (const float*)d_in[6];
    const float* b2  = (const float*)d_in[7];
    const float* Wc1 = (const float*)d_in[8];
    const float* bc1 = (const float*)d_in[9];
    const float* Wc2 = (const float*)d_in[10];
    const float* bc2 = (const float*)d_in[11];
    float* out = (float*)d_out;

    unsigned* S0 = (unsigned*)d_ws;
    unsigned* S1 = S0 + E;
    unsigned* S2 = S0 + 2 * E;
    unsigned* S3 = S0 + 3 * E;
    const long H2OFF = 32768L * 256;    // word offset of h2 rows inside H

    dim3 blk(512), sblk(256);

    // mlp1: T(S1) = leaky(X@W1+b1), X = [r1;r2] fp32 row-split
    gemm_k<1,0,2,0><<<dim3(512,2,1), blk, 0, stream>>>(
        (const unsigned*)r1, (const unsigned*)r2, (const unsigned*)W1, b1, S1,
        nullptr, nullptr, 65536,256,256,0, 256,256,256, 0,0,0);
    // mlp2: H(S2) = leaky(T@W2+b2) * rowmask
    gemm_k<0,0,3,0><<<dim3(512,2,1), blk, 0, stream>>>(
        S1, nullptr, (const unsigned*)W2, b2, S2,
        mk1, mk2, 65536,256,256,0, 256,256,256, 0,0,0);
    // scores: S(S0 fp32)[b] = h1[b] @ h2[b]^T
    gemm_k<0,1,0,0><<<dim3(4,4,64), blk, 0, stream>>>(
        S2, nullptr, S2 + H2OFF, nullptr, S0,
        nullptr, nullptr, 512,512,256,0, 256,256,512, 131072,131072,262144);
    // column softmax first (reads S0 -> S1), then row softmax IN-PLACE (S0)
    softmax_col_k<<<dim3(8,64), dim3(1024), 0, stream>>>(S0, mk1, mk2, S1);
    softmax_row_k<<<8192, sblk, 0, stream>>>(S0, mk1, mk2, S0);
    // rc1: RC(S3)[0:32768] = O1 @ h2
    gemm_k<0,2,1,0><<<dim3(4,2,64), blk, 0, stream>>>(
        S0, nullptr, S2 + H2OFF, nullptr, S3,
        nullptr, nullptr, 512,256,512,0, 512,256,256, 262144,131072,131072);
    // rc2: RC(S3)[32768:] = O2^T @ h1
    gemm_k<2,2,1,0><<<dim3(4,2,64), blk, 0, stream>>>(
        S1, nullptr, S2, nullptr, S3 + H2OFF,
        nullptr, nullptr, 512,256,512,0, 512,256,256, 262144,131072,131072);
    // cmp1: C1(S0) = leaky([H|RC] @ Wc1 + bc1)   (K-concat via DUALA)
    gemm_k<0,0,2,1><<<dim3(512,2,1), blk, 0, stream>>>(
        S2, S3, (const unsigned*)Wc1, bc1, S0,
        nullptr, nullptr, 65536,256,512,256, 256,256,256, 0,0,0);
    // cmp2: RCMP(S1 fp32) = leaky(C1 @ Wc2 + bc2)
    gemm_k<0,0,4,0><<<dim3(512,2,1), blk, 0, stream>>>(
        S0, nullptr, (const unsigned*)Wc2, bc2, S1,
        nullptr, nullptr, 65536,256,256,0, 256,256,256, 0,0,0);
    // masked mean-pool (partials into S2, then reduce)
    pool_part_k<<<dim3(8,64,2), sblk, 0, stream>>>((const float*)S1, mk1, mk2, (float*)S2);
    pool_red_k<<<128, sblk, 0, stream>>>((const float*)S2, mk1, mk2, out);
}